// Round 8
// baseline (120.003 us; speedup 1.0000x reference)
//
#include <hip/hip_runtime.h>
#include <hip/hip_bf16.h>

#define N_NODES 8192
#define F_IN    512
#define F_HID   256
#define ALPHA   0.2f
#define MAXDEG  64

using f32x4 = __attribute__((ext_vector_type(4))) float;
using f16x8 = __attribute__((ext_vector_type(8))) _Float16;
using f16x4 = __attribute__((ext_vector_type(4))) _Float16;

// ---------------------------------------------------------------------------
// Kernel 1 (prep): W1T/W2T fp16 transposes, w2s/w2t = W2 @ a2 halves,
// zero s1/t1 (atomic targets).
// ---------------------------------------------------------------------------
__global__ void prep_kernel(const float* __restrict__ W1, const float* __restrict__ W2,
                            _Float16* __restrict__ W1T, _Float16* __restrict__ W2T,
                            const float* __restrict__ a2,
                            float* __restrict__ w2s, float* __restrict__ w2t,
                            float* __restrict__ stz) {
    const int tid = threadIdx.x;
    int gid = blockIdx.x * 256 + tid;
    if (gid < 2 * N_NODES) stz[gid] = 0.0f;   // zero s1,t1

    if (blockIdx.x >= 256) {
        const int r = (blockIdx.x - 256) * 64 + (tid >> 2);   // 64 rows/block
        const int q = tid & 3;
        float ss = 0.f, tt = 0.f;
        for (int n = q * 4; n < F_IN; n += 16) {
            f32x4 w  = *(const f32x4*)&W2[(size_t)r * F_IN + n];
            f32x4 as = *(const f32x4*)&a2[n];
            f32x4 at = *(const f32x4*)&a2[F_IN + n];
            #pragma unroll
            for (int j = 0; j < 4; ++j) { ss += w[j] * as[j]; tt += w[j] * at[j]; }
        }
        ss += __shfl_xor(ss, 1); ss += __shfl_xor(ss, 2);
        tt += __shfl_xor(tt, 1); tt += __shfl_xor(tt, 2);
        if (q == 0) { w2s[r] = ss; w2t[r] = tt; }
        return;
    }

    int t = blockIdx.x;
    const float* W; _Float16* WT; int K, N, kt, nt;
    if (t < 128) { W = W1; WT = W1T; K = 512; N = 256; kt = t & 15; nt = t >> 4; }
    else { t -= 128; W = W2; WT = W2T; K = 256; N = 512; kt = t & 7; nt = t >> 3; }
    __shared__ float Ws[32][33];
    const int tx = tid & 31, ty = tid >> 5;  // 32 x 8
    #pragma unroll
    for (int i = 0; i < 4; ++i)
        Ws[ty + 8 * i][tx] = W[(size_t)(kt * 32 + ty + 8 * i) * N + nt * 32 + tx];
    __syncthreads();
    #pragma unroll
    for (int i = 0; i < 4; ++i)
        WT[(size_t)(nt * 32 + ty + 8 * i) * K + kt * 32 + tx] = (_Float16)Ws[tx][ty + 8 * i];
}

// ---------------------------------------------------------------------------
// CSR row scan (device): one wave per adjacency row. Writes global crow,
// optionally mirrors to LDS (jLds). Returns clamped degree (wave-uniform).
// ---------------------------------------------------------------------------
__device__ inline int csr_scan(const float* __restrict__ adj, int* __restrict__ crow,
                               int* jLds, int row, int lane) {
    const f32x4* arow = (const f32x4*)(adj + (size_t)row * N_NODES);
    int count = 0;
    const unsigned long long mlt = (1ULL << lane) - 1ULL;
    for (int base = 0; base < N_NODES; base += 512) {
        f32x4 v0 = __builtin_nontemporal_load(&arow[(base >> 2) + lane]);
        f32x4 v1 = __builtin_nontemporal_load(&arow[(base >> 2) + 64 + lane]);
        unsigned long long b0 = __ballot(v0[0] > 0.0f);
        unsigned long long b1 = __ballot(v0[1] > 0.0f);
        unsigned long long b2 = __ballot(v0[2] > 0.0f);
        unsigned long long b3 = __ballot(v0[3] > 0.0f);
        unsigned long long b4 = __ballot(v1[0] > 0.0f);
        unsigned long long b5 = __ballot(v1[1] > 0.0f);
        unsigned long long b6 = __ballot(v1[2] > 0.0f);
        unsigned long long b7 = __ballot(v1[3] > 0.0f);
        int o = count + __popcll(b0 & mlt) + __popcll(b1 & mlt)
                      + __popcll(b2 & mlt) + __popcll(b3 & mlt);
        int c0 = base + (lane << 2);
        if (v0[0] > 0.0f) { if (o < MAXDEG) { crow[o] = c0;     if (jLds) jLds[o] = c0;     } o++; }
        if (v0[1] > 0.0f) { if (o < MAXDEG) { crow[o] = c0 + 1; if (jLds) jLds[o] = c0 + 1; } o++; }
        if (v0[2] > 0.0f) { if (o < MAXDEG) { crow[o] = c0 + 2; if (jLds) jLds[o] = c0 + 2; } o++; }
        if (v0[3] > 0.0f) { if (o < MAXDEG) { crow[o] = c0 + 3; if (jLds) jLds[o] = c0 + 3; } o++; }
        count += __popcll(b0) + __popcll(b1) + __popcll(b2) + __popcll(b3);
        o = count + __popcll(b4 & mlt) + __popcll(b5 & mlt)
                  + __popcll(b6 & mlt) + __popcll(b7 & mlt);
        int c1 = base + 256 + (lane << 2);
        if (v1[0] > 0.0f) { if (o < MAXDEG) { crow[o] = c1;     if (jLds) jLds[o] = c1;     } o++; }
        if (v1[1] > 0.0f) { if (o < MAXDEG) { crow[o] = c1 + 1; if (jLds) jLds[o] = c1 + 1; } o++; }
        if (v1[2] > 0.0f) { if (o < MAXDEG) { crow[o] = c1 + 2; if (jLds) jLds[o] = c1 + 2; } o++; }
        if (v1[3] > 0.0f) { if (o < MAXDEG) { crow[o] = c1 + 3; if (jLds) jLds[o] = c1 + 3; } o++; }
        count += __popcll(b4) + __popcll(b5) + __popcll(b6) + __popcll(b7);
    }
    return count > MAXDEG ? MAXDEG : count;
}

// ---------------------------------------------------------------------------
// GEMM1 tile (device): Wh1[64 x 128] fp16 = x(f32->f16) @ W1T cols tile.
// BM=64, BN=128, BK=64; 4 waves (2m x 2n), wave tile 32x64 (acc 2x4).
// Epilogue: atomic s1/t1 contribution for this col-tile.
// ---------------------------------------------------------------------------
__device__ inline void gemm1_tile(const float* __restrict__ x,
                                  const _Float16* __restrict__ W1T,
                                  _Float16* __restrict__ Wh1,
                                  const float* __restrict__ a1,
                                  float* __restrict__ s1, float* __restrict__ t1,
                                  int brow, int bcol) {
    const int LDT = 72;
    __shared__ _Float16 As[64 * LDT];
    __shared__ _Float16 Bs[128 * LDT];
    const int tid = threadIdx.x;
    const int wid = tid >> 6, lane = tid & 63;
    const int wr = (wid >> 1) * 32, wc = (wid & 1) * 64;
    const int sr = tid >> 3, skg = (tid & 7) * 8;

    f32x4 acc[2][4];
    #pragma unroll
    for (int m = 0; m < 2; ++m)
        #pragma unroll
        for (int n = 0; n < 4; ++n) acc[m][n] = f32x4{0.f, 0.f, 0.f, 0.f};

    for (int k0 = 0; k0 < F_IN; k0 += 64) {
        #pragma unroll
        for (int i = 0; i < 2; ++i) {
            int r = sr + i * 32;
            const f32x4* src = (const f32x4*)(x + (size_t)(brow + r) * F_IN + k0 + skg);
            f32x4 a0 = src[0];
            f32x4 a1v = src[1];
            f16x8 av;
            #pragma unroll
            for (int j = 0; j < 4; ++j) { av[j] = (_Float16)a0[j]; av[4 + j] = (_Float16)a1v[j]; }
            *(f16x8*)&As[r * LDT + skg] = av;
        }
        #pragma unroll
        for (int i = 0; i < 4; ++i) {
            int r = sr + i * 32;
            *(f16x8*)&Bs[r * LDT + skg] =
                *(const f16x8*)&W1T[(size_t)(bcol + r) * F_IN + k0 + skg];
        }
        __syncthreads();
        #pragma unroll
        for (int ks = 0; ks < 2; ++ks) {
            const int kb = ks * 32 + (lane >> 4) * 8;
            f16x8 af[2], bfr[4];
            #pragma unroll
            for (int m = 0; m < 2; ++m)
                af[m] = *(const f16x8*)&As[(wr + m * 16 + (lane & 15)) * LDT + kb];
            #pragma unroll
            for (int n = 0; n < 4; ++n)
                bfr[n] = *(const f16x8*)&Bs[(wc + n * 16 + (lane & 15)) * LDT + kb];
            #pragma unroll
            for (int m = 0; m < 2; ++m)
                #pragma unroll
                for (int n = 0; n < 4; ++n)
                    acc[m][n] = __builtin_amdgcn_mfma_f32_16x16x32_f16(
                        af[m], bfr[n], acc[m][n], 0, 0, 0);
        }
        __syncthreads();
    }
    const int cl = lane & 15;
    float as[4], at[4];
    #pragma unroll
    for (int n = 0; n < 4; ++n) {
        as[n] = a1[bcol + wc + n * 16 + cl];
        at[n] = a1[F_HID + bcol + wc + n * 16 + cl];
    }
    #pragma unroll
    for (int m = 0; m < 2; ++m) {
        #pragma unroll
        for (int j = 0; j < 4; ++j) {
            float vs = 0.f, vt = 0.f;
            #pragma unroll
            for (int n = 0; n < 4; ++n) { vs += acc[m][n][j] * as[n]; vt += acc[m][n][j] * at[n]; }
            #pragma unroll
            for (int off = 1; off < 16; off <<= 1) {
                vs += __shfl_xor(vs, off);
                vt += __shfl_xor(vt, off);
            }
            if (cl == 0) {
                int row = brow + wr + m * 16 + ((lane >> 4) << 2) + j;
                atomicAdd(s1 + row, vs);
                atomicAdd(t1 + row, vt);
            }
        }
        #pragma unroll
        for (int n = 0; n < 4; ++n) {
            int row = brow + wr + m * 16 + ((lane >> 4) << 2);
            int col = bcol + wc + n * 16 + cl;
            #pragma unroll
            for (int j = 0; j < 4; ++j)
                Wh1[(size_t)(row + j) * F_HID + col] = (_Float16)acc[m][n][j];
        }
    }
}

// ---------------------------------------------------------------------------
// Kernel 2: GEMM1 (256 tile jobs) + CSR for rows 0..4095 (1024 quads).
// ---------------------------------------------------------------------------
__global__ __launch_bounds__(256)
void gemm1_csr(const float* __restrict__ adj, int* __restrict__ cols,
               int* __restrict__ cnt, const float* __restrict__ x,
               const _Float16* __restrict__ W1T, _Float16* __restrict__ Wh1,
               const float* __restrict__ a1,
               float* __restrict__ s1, float* __restrict__ t1) {
    const int bid = blockIdx.x;
    const int g = bid / 5, r = bid % 5;
    if (r == 0) {
        gemm1_tile(x, W1T, Wh1, a1, s1, t1, (g & 127) * 64, (g >> 7) * 128);
    } else {
        const int q = g * 4 + (r - 1);                  // quad in [0, 1024)
        const int row = q * 4 + (threadIdx.x >> 6);
        const int lane = threadIdx.x & 63;
        int deg = csr_scan(adj, cols + (size_t)row * MAXDEG, nullptr, row, lane);
        if (lane == 0) cnt[row] = deg;
    }
}

// ---------------------------------------------------------------------------
// Kernel 3: layer-1 attention for ALL rows; even blocks also csr-scan rows
// 4096..8191 first (adj HBM stream overlaps other blocks' L2 gathers).
// Epilogue: s2/t2 = enc_row . w2s/w2t.
// ---------------------------------------------------------------------------
__global__ __launch_bounds__(256)
void csr_agg1(const float* __restrict__ adj, int* __restrict__ cols,
              int* __restrict__ cnt, const _Float16* __restrict__ Wh1,
              const float* __restrict__ s1, const float* __restrict__ t1,
              const float* __restrict__ w2s, const float* __restrict__ w2t,
              float* __restrict__ enc, _Float16* __restrict__ enc16,
              float* __restrict__ s2, float* __restrict__ t2) {
    const int bid = blockIdx.x;
    const int wid = threadIdx.x >> 6, lane = threadIdx.x & 63;
    const bool doCsr = !(bid & 1);
    const int quad = doCsr ? 1024 + (bid >> 1) : (bid >> 1);
    const int row = quad * 4 + wid;
    __shared__ int jS[4][64];
    __shared__ float pS[4][64];

    int deg;
    if (doCsr) {
        deg = csr_scan(adj, cols + (size_t)row * MAXDEG, jS[wid], row, lane);
        if (lane == 0) cnt[row] = deg;
    } else {
        deg = cnt[row];
        if (lane < deg) jS[wid][lane] = cols[(size_t)row * MAXDEG + lane];
    }

    const float sI = s1[row];
    float ev = -1e30f;
    if (lane < deg) {
        float z = sI + t1[jS[wid][lane]];
        ev = z > 0.0f ? z : ALPHA * z;
    }
    float m = ev;
    #pragma unroll
    for (int off = 32; off > 0; off >>= 1) m = fmaxf(m, __shfl_xor(m, off));
    float ex = (lane < deg) ? __expf(ev - m) : 0.0f;
    float sum = ex;
    #pragma unroll
    for (int off = 32; off > 0; off >>= 1) sum += __shfl_xor(sum, off);
    pS[wid][lane] = ex / sum;

    float acc[4] = {};
    const size_t lo = (size_t)lane * 4;
    int d = 0;
    for (; d + 4 <= deg; d += 4) {
        float p0 = pS[wid][d],     p1 = pS[wid][d + 1];
        float p2 = pS[wid][d + 2], p3 = pS[wid][d + 3];
        f16x4 v0 = *(const f16x4*)(Wh1 + (size_t)jS[wid][d] * F_HID + lo);
        f16x4 v1 = *(const f16x4*)(Wh1 + (size_t)jS[wid][d + 1] * F_HID + lo);
        f16x4 v2 = *(const f16x4*)(Wh1 + (size_t)jS[wid][d + 2] * F_HID + lo);
        f16x4 v3 = *(const f16x4*)(Wh1 + (size_t)jS[wid][d + 3] * F_HID + lo);
        #pragma unroll
        for (int jj = 0; jj < 4; ++jj)
            acc[jj] += p0 * (float)v0[jj] + p1 * (float)v1[jj]
                     + p2 * (float)v2[jj] + p3 * (float)v3[jj];
    }
    for (; d < deg; ++d) {
        float p = pS[wid][d];
        f16x4 w = *(const f16x4*)(Wh1 + (size_t)jS[wid][d] * F_HID + lo);
        #pragma unroll
        for (int jj = 0; jj < 4; ++jj) acc[jj] += p * (float)w[jj];
    }
    f32x4 o; f16x4 h;
    #pragma unroll
    for (int jj = 0; jj < 4; ++jj) {
        float v = acc[jj];
        float e = v > 0.0f ? v : (__expf(v) - 1.0f);
        o[jj] = e; h[jj] = (_Float16)e;
    }
    __builtin_nontemporal_store(o, (f32x4*)(enc + (size_t)row * F_HID + lo));
    *(f16x4*)(enc16 + (size_t)row * F_HID + lo) = h;

    f32x4 ws = *(const f32x4*)(w2s + lo);
    f32x4 wt = *(const f32x4*)(w2t + lo);
    float ps = 0.f, pt = 0.f;
    #pragma unroll
    for (int jj = 0; jj < 4; ++jj) { ps += o[jj] * ws[jj]; pt += o[jj] * wt[jj]; }
    #pragma unroll
    for (int off = 32; off > 0; off >>= 1) {
        ps += __shfl_xor(ps, off);
        pt += __shfl_xor(pt, off);
    }
    if (lane == 0) { s2[row] = ps; t2[row] = pt; }
}

// ---------------------------------------------------------------------------
// Kernel 4: fused layer-2. 16-row slab per block: softmax(s2,t2) + gather
// enc16 -> aggE in LDS (fp16, MFMA A operand) -> x W2T -> elu -> dec.
// ---------------------------------------------------------------------------
__global__ __launch_bounds__(256)
void l2_fused(const _Float16* __restrict__ enc16, const _Float16* __restrict__ W2T,
              const int* __restrict__ cols, const int* __restrict__ cnt,
              const float* __restrict__ s2, const float* __restrict__ t2,
              float* __restrict__ dec) {
    const int LDA = 264, LDB = 264;
    __shared__ _Float16 aggE[16 * LDA];    // 8.4 KB
    __shared__ _Float16 Bs[64 * LDB];      // 33.8 KB
    const int base = blockIdx.x * 16;
    const int wid = threadIdx.x >> 6, lane = threadIdx.x & 63;

    // phase A: wave wid aggregates rows base+wid*4 .. +4
    for (int rr = 0; rr < 4; ++rr) {
        const int row = base + wid * 4 + rr;
        const int deg = cnt[row];
        const float sI = s2[row];
        int j = 0;
        float ev = -1e30f;
        if (lane < deg) {
            j = cols[(size_t)row * MAXDEG + lane];
            float z = sI + t2[j];
            ev = z > 0.0f ? z : ALPHA * z;
        }
        float m = ev;
        #pragma unroll
        for (int off = 32; off > 0; off >>= 1) m = fmaxf(m, __shfl_xor(m, off));
        float ex = (lane < deg) ? __expf(ev - m) : 0.0f;
        float sum = ex;
        #pragma unroll
        for (int off = 32; off > 0; off >>= 1) sum += __shfl_xor(sum, off);
        float p = ex / sum;

        float acc[4] = {};
        const size_t lo = (size_t)lane * 4;
        int d = 0;
        for (; d + 4 <= deg; d += 4) {
            float p0 = __shfl(p, d),     p1 = __shfl(p, d + 1);
            float p2 = __shfl(p, d + 2), p3 = __shfl(p, d + 3);
            int j0 = __shfl(j, d),     j1 = __shfl(j, d + 1);
            int j2 = __shfl(j, d + 2), j3 = __shfl(j, d + 3);
            f16x4 v0 = *(const f16x4*)(enc16 + (size_t)j0 * F_HID + lo);
            f16x4 v1 = *(const f16x4*)(enc16 + (size_t)j1 * F_HID + lo);
            f16x4 v2 = *(const f16x4*)(enc16 + (size_t)j2 * F_HID + lo);
            f16x4 v3 = *(const f16x4*)(enc16 + (size_t)j3 * F_HID + lo);
            #pragma unroll
            for (int jj = 0; jj < 4; ++jj)
                acc[jj] += p0 * (float)v0[jj] + p1 * (float)v1[jj]
                         + p2 * (float)v2[jj] + p3 * (float)v3[jj];
        }
        for (; d < deg; ++d) {
            float pd = __shfl(p, d);
            int jd = __shfl(j, d);
            f16x4 v = *(const f16x4*)(enc16 + (size_t)jd * F_HID + lo);
            #pragma unroll
            for (int jj = 0; jj < 4; ++jj) acc[jj] += pd * (float)v[jj];
        }
        f16x4 h;
        #pragma unroll
        for (int jj = 0; jj < 4; ++jj) h[jj] = (_Float16)acc[jj];
        *(f16x4*)&aggE[(wid * 4 + rr) * LDA + lane * 4] = h;
    }
    __syncthreads();

    // hoist A fragments: row = lane&15, 8 k-frags of 32
    f16x8 af[8];
    #pragma unroll
    for (int kf = 0; kf < 8; ++kf)
        af[kf] = *(const f16x8*)&aggE[(lane & 15) * LDA + kf * 32 + (lane >> 4) * 8];

    // phase B: 8 col-tiles of 64; wave wid covers 16 cols of each tile
    for (int ct = 0; ct < 8; ++ct) {
        #pragma unroll
        for (int i = 0; i < 8; ++i) {
            int idx = threadIdx.x + i * 256;
            int c = idx >> 5, kg = (idx & 31) * 8;
            *(f16x8*)&Bs[c * LDB + kg] =
                *(const f16x8*)&W2T[(size_t)(ct * 64 + c) * F_HID + kg];
        }
        __syncthreads();
        f32x4 oacc = f32x4{0.f, 0.f, 0.f, 0.f};
        #pragma unroll
        for (int kf = 0; kf < 8; ++kf) {
            f16x8 bf = *(const f16x8*)&Bs[(wid * 16 + (lane & 15)) * LDB
                                          + kf * 32 + (lane >> 4) * 8];
            oacc = __builtin_amdgcn_mfma_f32_16x16x32_f16(af[kf], bf, oacc, 0, 0, 0);
        }
        const int col = ct * 64 + wid * 16 + (lane & 15);
        const int row0 = base + ((lane >> 4) << 2);
        #pragma unroll
        for (int jj = 0; jj < 4; ++jj) {
            float v = oacc[jj];
            float e = v > 0.0f ? v : (__expf(v) - 1.0f);
            __builtin_nontemporal_store(e, &dec[(size_t)(row0 + jj) * F_IN + col]);
        }
        __syncthreads();
    }
}

// ---------------------------------------------------------------------------
extern "C" void kernel_launch(void* const* d_in, const int* in_sizes, int n_in,
                              void* d_out, int out_size, void* d_ws, size_t ws_size,
                              hipStream_t stream) {
    (void)in_sizes; (void)n_in; (void)out_size; (void)ws_size;
    const float* x   = (const float*)d_in[0];
    const float* adj = (const float*)d_in[1];
    const float* W1  = (const float*)d_in[2];
    const float* a1  = (const float*)d_in[3];
    const float* W2  = (const float*)d_in[4];
    const float* a2  = (const float*)d_in[5];

    float* dec = (float*)d_out;                           // [8192, 512] f32
    float* enc = dec + (size_t)N_NODES * F_IN;            // [8192, 256] f32

    int*      cols  = (int*)d_ws;                         // 8192*64
    int*      cnt   = cols + (size_t)N_NODES * MAXDEG;    // 8192
    float*    s1    = (float*)(cnt + N_NODES);            // 8192
    float*    t1    = s1 + N_NODES;                       // 8192
    float*    s2    = t1 + N_NODES;                       // 8192
    float*    t2    = s2 + N_NODES;                       // 8192
    float*    w2s   = t2 + N_NODES;                       // 256
    float*    w2t   = w2s + F_HID;                        // 256
    _Float16* Wh1   = (_Float16*)(w2t + F_HID);           // 8192*256 fp16
    _Float16* enc16 = Wh1 + (size_t)N_NODES * F_HID;      // 8192*256 fp16
    _Float16* W1T   = enc16 + (size_t)N_NODES * F_HID;    // 256*512 fp16
    _Float16* W2T   = W1T + (size_t)F_HID * F_IN;         // 512*256 fp16

    // 1. prep: transposes, w2s/w2t, zero s1/t1
    prep_kernel<<<260, 256, 0, stream>>>(W1, W2, W1T, W2T, a2, w2s, w2t, s1);

    // 2. gemm1 (BN=128, 256 jobs) + csr rows 0..4095 (1024 quads)
    gemm1_csr<<<1280, 256, 0, stream>>>(adj, cols, cnt, x, W1T, Wh1, a1, s1, t1);

    // 3. csr rows 4096..8191 fused with layer-1 attention for all rows
    csr_agg1<<<2048, 256, 0, stream>>>(adj, cols, cnt, Wh1, s1, t1,
                                       w2s, w2t, enc, enc16, s2, t2);

    // 4. fused layer-2: aggregate enc16 (LDS) -> @W2 -> elu -> dec
    l2_fused<<<N_NODES / 16, 256, 0, stream>>>(enc16, W2T, cols, cnt, s2, t2, dec);
}

// Round 9
// 100.329 us; speedup vs baseline: 1.1961x; 1.1961x over previous
//
#include <hip/hip_runtime.h>
#include <hip/hip_bf16.h>

#define N_NODES 8192
#define F_IN    512
#define F_HID   256
#define ALPHA   0.2f
#define MAXDEG  64

using f32x4 = __attribute__((ext_vector_type(4))) float;
using f16x8 = __attribute__((ext_vector_type(8))) _Float16;
using f16x4 = __attribute__((ext_vector_type(4))) _Float16;

// ---------------------------------------------------------------------------
// Kernel 1 (prep): W1T/W2T fp16 transposes, w2s/w2t = W2 @ a2 halves,
// zero s1/t1 (atomic targets).
// ---------------------------------------------------------------------------
__global__ void prep_kernel(const float* __restrict__ W1, const float* __restrict__ W2,
                            _Float16* __restrict__ W1T, _Float16* __restrict__ W2T,
                            const float* __restrict__ a2,
                            float* __restrict__ w2s, float* __restrict__ w2t,
                            float* __restrict__ stz) {
    const int tid = threadIdx.x;
    int gid = blockIdx.x * 256 + tid;
    if (gid < 2 * N_NODES) stz[gid] = 0.0f;   // zero s1,t1

    if (blockIdx.x >= 256) {
        const int r = (blockIdx.x - 256) * 64 + (tid >> 2);   // 64 rows/block
        const int q = tid & 3;
        float ss = 0.f, tt = 0.f;
        for (int n = q * 4; n < F_IN; n += 16) {
            f32x4 w  = *(const f32x4*)&W2[(size_t)r * F_IN + n];
            f32x4 as = *(const f32x4*)&a2[n];
            f32x4 at = *(const f32x4*)&a2[F_IN + n];
            #pragma unroll
            for (int j = 0; j < 4; ++j) { ss += w[j] * as[j]; tt += w[j] * at[j]; }
        }
        ss += __shfl_xor(ss, 1); ss += __shfl_xor(ss, 2);
        tt += __shfl_xor(tt, 1); tt += __shfl_xor(tt, 2);
        if (q == 0) { w2s[r] = ss; w2t[r] = tt; }
        return;
    }

    int t = blockIdx.x;
    const float* W; _Float16* WT; int K, N, kt, nt;
    if (t < 128) { W = W1; WT = W1T; K = 512; N = 256; kt = t & 15; nt = t >> 4; }
    else { t -= 128; W = W2; WT = W2T; K = 256; N = 512; kt = t & 7; nt = t >> 3; }
    __shared__ float Ws[32][33];
    const int tx = tid & 31, ty = tid >> 5;  // 32 x 8
    #pragma unroll
    for (int i = 0; i < 4; ++i)
        Ws[ty + 8 * i][tx] = W[(size_t)(kt * 32 + ty + 8 * i) * N + nt * 32 + tx];
    __syncthreads();
    #pragma unroll
    for (int i = 0; i < 4; ++i)
        WT[(size_t)(nt * 32 + ty + 8 * i) * K + kt * 32 + tx] = (_Float16)Ws[tx][ty + 8 * i];
}

// ---------------------------------------------------------------------------
// CSR row scan (device): one wave per adjacency row.
// ---------------------------------------------------------------------------
__device__ inline void csr_row(const float* __restrict__ adj, int* __restrict__ cols,
                               int* __restrict__ cnt, int row, int lane) {
    const f32x4* arow = (const f32x4*)(adj + (size_t)row * N_NODES);
    int* crow = cols + (size_t)row * MAXDEG;
    int count = 0;
    const unsigned long long mlt = (1ULL << lane) - 1ULL;
    for (int base = 0; base < N_NODES; base += 512) {
        f32x4 v0 = __builtin_nontemporal_load(&arow[(base >> 2) + lane]);
        f32x4 v1 = __builtin_nontemporal_load(&arow[(base >> 2) + 64 + lane]);
        unsigned long long b0 = __ballot(v0[0] > 0.0f);
        unsigned long long b1 = __ballot(v0[1] > 0.0f);
        unsigned long long b2 = __ballot(v0[2] > 0.0f);
        unsigned long long b3 = __ballot(v0[3] > 0.0f);
        unsigned long long b4 = __ballot(v1[0] > 0.0f);
        unsigned long long b5 = __ballot(v1[1] > 0.0f);
        unsigned long long b6 = __ballot(v1[2] > 0.0f);
        unsigned long long b7 = __ballot(v1[3] > 0.0f);
        int o = count + __popcll(b0 & mlt) + __popcll(b1 & mlt)
                      + __popcll(b2 & mlt) + __popcll(b3 & mlt);
        int c0 = base + (lane << 2);
        if (v0[0] > 0.0f) { if (o < MAXDEG) crow[o] = c0;     o++; }
        if (v0[1] > 0.0f) { if (o < MAXDEG) crow[o] = c0 + 1; o++; }
        if (v0[2] > 0.0f) { if (o < MAXDEG) crow[o] = c0 + 2; o++; }
        if (v0[3] > 0.0f) { if (o < MAXDEG) crow[o] = c0 + 3; o++; }
        count += __popcll(b0) + __popcll(b1) + __popcll(b2) + __popcll(b3);
        o = count + __popcll(b4 & mlt) + __popcll(b5 & mlt)
                  + __popcll(b6 & mlt) + __popcll(b7 & mlt);
        int c1 = base + 256 + (lane << 2);
        if (v1[0] > 0.0f) { if (o < MAXDEG) crow[o] = c1;     o++; }
        if (v1[1] > 0.0f) { if (o < MAXDEG) crow[o] = c1 + 1; o++; }
        if (v1[2] > 0.0f) { if (o < MAXDEG) crow[o] = c1 + 2; o++; }
        if (v1[3] > 0.0f) { if (o < MAXDEG) crow[o] = c1 + 3; o++; }
        count += __popcll(b4) + __popcll(b5) + __popcll(b6) + __popcll(b7);
    }
    if (lane == 0) cnt[row] = count > MAXDEG ? MAXDEG : count;
}

// ---------------------------------------------------------------------------
// GEMM1 tile (device): Wh1[64 x 128] fp16 = x(f32->f16) @ W1T col-tile.
// BM=64, BN=128, BK=64; 4 waves (2m x 2n), wave tile 32x64 (acc 2x4).
// Epilogue: atomic s1/t1 contribution for this col-tile.
// ---------------------------------------------------------------------------
__device__ inline void gemm1_tile(const float* __restrict__ x,
                                  const _Float16* __restrict__ W1T,
                                  _Float16* __restrict__ Wh1,
                                  const float* __restrict__ a1,
                                  float* __restrict__ s1, float* __restrict__ t1,
                                  int brow, int bcol) {
    const int LDT = 72;
    __shared__ _Float16 As[64 * LDT];
    __shared__ _Float16 Bs[128 * LDT];
    const int tid = threadIdx.x;
    const int wid = tid >> 6, lane = tid & 63;
    const int wr = (wid >> 1) * 32, wc = (wid & 1) * 64;
    const int sr = tid >> 3, skg = (tid & 7) * 8;

    f32x4 acc[2][4];
    #pragma unroll
    for (int m = 0; m < 2; ++m)
        #pragma unroll
        for (int n = 0; n < 4; ++n) acc[m][n] = f32x4{0.f, 0.f, 0.f, 0.f};

    for (int k0 = 0; k0 < F_IN; k0 += 64) {
        #pragma unroll
        for (int i = 0; i < 2; ++i) {
            int r = sr + i * 32;
            const f32x4* src = (const f32x4*)(x + (size_t)(brow + r) * F_IN + k0 + skg);
            f32x4 a0 = src[0];
            f32x4 a1v = src[1];
            f16x8 av;
            #pragma unroll
            for (int j = 0; j < 4; ++j) { av[j] = (_Float16)a0[j]; av[4 + j] = (_Float16)a1v[j]; }
            *(f16x8*)&As[r * LDT + skg] = av;
        }
        #pragma unroll
        for (int i = 0; i < 4; ++i) {
            int r = sr + i * 32;
            *(f16x8*)&Bs[r * LDT + skg] =
                *(const f16x8*)&W1T[(size_t)(bcol + r) * F_IN + k0 + skg];
        }
        __syncthreads();
        #pragma unroll
        for (int ks = 0; ks < 2; ++ks) {
            const int kb = ks * 32 + (lane >> 4) * 8;
            f16x8 af[2], bfr[4];
            #pragma unroll
            for (int m = 0; m < 2; ++m)
                af[m] = *(const f16x8*)&As[(wr + m * 16 + (lane & 15)) * LDT + kb];
            #pragma unroll
            for (int n = 0; n < 4; ++n)
                bfr[n] = *(const f16x8*)&Bs[(wc + n * 16 + (lane & 15)) * LDT + kb];
            #pragma unroll
            for (int m = 0; m < 2; ++m)
                #pragma unroll
                for (int n = 0; n < 4; ++n)
                    acc[m][n] = __builtin_amdgcn_mfma_f32_16x16x32_f16(
                        af[m], bfr[n], acc[m][n], 0, 0, 0);
        }
        __syncthreads();
    }
    const int cl = lane & 15;
    float as[4], at[4];
    #pragma unroll
    for (int n = 0; n < 4; ++n) {
        as[n] = a1[bcol + wc + n * 16 + cl];
        at[n] = a1[F_HID + bcol + wc + n * 16 + cl];
    }
    #pragma unroll
    for (int m = 0; m < 2; ++m) {
        #pragma unroll
        for (int j = 0; j < 4; ++j) {
            float vs = 0.f, vt = 0.f;
            #pragma unroll
            for (int n = 0; n < 4; ++n) { vs += acc[m][n][j] * as[n]; vt += acc[m][n][j] * at[n]; }
            #pragma unroll
            for (int off = 1; off < 16; off <<= 1) {
                vs += __shfl_xor(vs, off);
                vt += __shfl_xor(vt, off);
            }
            if (cl == 0) {
                int row = brow + wr + m * 16 + ((lane >> 4) << 2) + j;
                atomicAdd(s1 + row, vs);
                atomicAdd(t1 + row, vt);
            }
        }
        #pragma unroll
        for (int n = 0; n < 4; ++n) {
            int row = brow + wr + m * 16 + ((lane >> 4) << 2);
            int col = bcol + wc + n * 16 + cl;
            #pragma unroll
            for (int j = 0; j < 4; ++j)
                Wh1[(size_t)(row + j) * F_HID + col] = (_Float16)acc[m][n][j];
        }
    }
}

// ---------------------------------------------------------------------------
// Kernel 2: csr scan (ALL 8192 rows, HBM-bound) co-scheduled with GEMM1
// (256 tile jobs, MFMA-bound). GEMM jobs at LOW blockIds so they enter the
// first scheduling round and finish under the csr stream (no stragglers).
// ---------------------------------------------------------------------------
__global__ __launch_bounds__(256)
void csr_and_gemm1(const float* __restrict__ adj, int* __restrict__ cols,
                   int* __restrict__ cnt, const float* __restrict__ x,
                   const _Float16* __restrict__ W1T, _Float16* __restrict__ Wh1,
                   const float* __restrict__ a1,
                   float* __restrict__ s1, float* __restrict__ t1) {
    const int bid = blockIdx.x;
    if (bid < 256) {
        // 128 row-tiles x 2 col-tiles
        gemm1_tile(x, W1T, Wh1, a1, s1, t1, (bid & 127) * 64, (bid >> 7) * 128);
    } else {
        const int q = bid - 256;                        // quad in [0, 2048)
        const int row = q * 4 + (threadIdx.x >> 6);
        csr_row(adj, cols, cnt, row, threadIdx.x & 63);
    }
}

// ---------------------------------------------------------------------------
// Kernel 3: layer-1 aggregate: softmax(s1,t1), gather Wh1 (L2-hot 4 MB),
// ELU, write enc (f32 NT) + enc16; epilogue s2/t2 = enc_row . w2s/w2t.
// ---------------------------------------------------------------------------
__global__ void aggregate_l1(const _Float16* __restrict__ Wh,
                             const int* __restrict__ cols, const int* __restrict__ cnt,
                             const float* __restrict__ s, const float* __restrict__ t,
                             const float* __restrict__ w2s, const float* __restrict__ w2t,
                             float* __restrict__ enc, _Float16* __restrict__ enc16,
                             float* __restrict__ s2, float* __restrict__ t2) {
    const int wid = threadIdx.x >> 6, lane = threadIdx.x & 63;
    const int row = blockIdx.x * 4 + wid;
    const int deg = cnt[row];
    __shared__ float pS[4][64];
    __shared__ int jS[4][64];
    int j = 0;
    float ev = -1e30f;
    if (lane < deg) {
        j = cols[(size_t)row * MAXDEG + lane];
        float z = s[row] + t[j];
        ev = z > 0.0f ? z : ALPHA * z;
    }
    float m = ev;
    #pragma unroll
    for (int off = 32; off > 0; off >>= 1) m = fmaxf(m, __shfl_xor(m, off));
    float ex = (lane < deg) ? __expf(ev - m) : 0.0f;
    float sum = ex;
    #pragma unroll
    for (int off = 32; off > 0; off >>= 1) sum += __shfl_xor(sum, off);
    pS[wid][lane] = ex / sum;
    jS[wid][lane] = j;
    __syncthreads();

    float acc[4] = {};
    const size_t lo = (size_t)lane * 4;
    int d = 0;
    for (; d + 4 <= deg; d += 4) {
        float p0 = pS[wid][d],     p1 = pS[wid][d + 1];
        float p2 = pS[wid][d + 2], p3 = pS[wid][d + 3];
        f16x4 v0 = *(const f16x4*)(Wh + (size_t)jS[wid][d] * F_HID + lo);
        f16x4 v1 = *(const f16x4*)(Wh + (size_t)jS[wid][d + 1] * F_HID + lo);
        f16x4 v2 = *(const f16x4*)(Wh + (size_t)jS[wid][d + 2] * F_HID + lo);
        f16x4 v3 = *(const f16x4*)(Wh + (size_t)jS[wid][d + 3] * F_HID + lo);
        #pragma unroll
        for (int jj = 0; jj < 4; ++jj)
            acc[jj] += p0 * (float)v0[jj] + p1 * (float)v1[jj]
                     + p2 * (float)v2[jj] + p3 * (float)v3[jj];
    }
    for (; d < deg; ++d) {
        float p = pS[wid][d];
        f16x4 w = *(const f16x4*)(Wh + (size_t)jS[wid][d] * F_HID + lo);
        #pragma unroll
        for (int jj = 0; jj < 4; ++jj) acc[jj] += p * (float)w[jj];
    }
    f32x4 o; f16x4 h;
    #pragma unroll
    for (int jj = 0; jj < 4; ++jj) {
        float v = acc[jj];
        float e = v > 0.0f ? v : (__expf(v) - 1.0f);
        o[jj] = e; h[jj] = (_Float16)e;
    }
    __builtin_nontemporal_store(o, (f32x4*)(enc + (size_t)row * F_HID + lo));
    *(f16x4*)(enc16 + (size_t)row * F_HID + lo) = h;

    f32x4 ws = *(const f32x4*)(w2s + lo);
    f32x4 wt = *(const f32x4*)(w2t + lo);
    float ps = 0.f, pt = 0.f;
    #pragma unroll
    for (int jj = 0; jj < 4; ++jj) { ps += o[jj] * ws[jj]; pt += o[jj] * wt[jj]; }
    #pragma unroll
    for (int off = 32; off > 0; off >>= 1) {
        ps += __shfl_xor(ps, off);
        pt += __shfl_xor(pt, off);
    }
    if (lane == 0) { s2[row] = ps; t2[row] = pt; }
}

// ---------------------------------------------------------------------------
// Kernel 4: layer-2 pre-aggregate in input space (linearity of attention):
// aggE = att2 @ enc. Gathers enc16 (L2-hot 4 MB). No ELU here.
// ---------------------------------------------------------------------------
__global__ void aggregate_l2pre(const _Float16* __restrict__ enc16,
                                const int* __restrict__ cols, const int* __restrict__ cnt,
                                const float* __restrict__ s, const float* __restrict__ t,
                                _Float16* __restrict__ aggE16) {
    const int wid = threadIdx.x >> 6, lane = threadIdx.x & 63;
    const int row = blockIdx.x * 4 + wid;
    const int deg = cnt[row];
    __shared__ float pS[4][64];
    __shared__ int jS[4][64];
    int j = 0;
    float ev = -1e30f;
    if (lane < deg) {
        j = cols[(size_t)row * MAXDEG + lane];
        float z = s[row] + t[j];
        ev = z > 0.0f ? z : ALPHA * z;
    }
    float m = ev;
    #pragma unroll
    for (int off = 32; off > 0; off >>= 1) m = fmaxf(m, __shfl_xor(m, off));
    float ex = (lane < deg) ? __expf(ev - m) : 0.0f;
    float sum = ex;
    #pragma unroll
    for (int off = 32; off > 0; off >>= 1) sum += __shfl_xor(sum, off);
    pS[wid][lane] = ex / sum;
    jS[wid][lane] = j;
    __syncthreads();

    float acc[4] = {};
    const size_t lo = (size_t)lane * 4;
    int d = 0;
    for (; d + 4 <= deg; d += 4) {
        float p0 = pS[wid][d],     p1 = pS[wid][d + 1];
        float p2 = pS[wid][d + 2], p3 = pS[wid][d + 3];
        f16x4 v0 = *(const f16x4*)(enc16 + (size_t)jS[wid][d] * F_HID + lo);
        f16x4 v1 = *(const f16x4*)(enc16 + (size_t)jS[wid][d + 1] * F_HID + lo);
        f16x4 v2 = *(const f16x4*)(enc16 + (size_t)jS[wid][d + 2] * F_HID + lo);
        f16x4 v3 = *(const f16x4*)(enc16 + (size_t)jS[wid][d + 3] * F_HID + lo);
        #pragma unroll
        for (int jj = 0; jj < 4; ++jj)
            acc[jj] += p0 * (float)v0[jj] + p1 * (float)v1[jj]
                     + p2 * (float)v2[jj] + p3 * (float)v3[jj];
    }
    for (; d < deg; ++d) {
        float p = pS[wid][d];
        f16x4 w = *(const f16x4*)(enc16 + (size_t)jS[wid][d] * F_HID + lo);
        #pragma unroll
        for (int jj = 0; jj < 4; ++jj) acc[jj] += p * (float)w[jj];
    }
    f16x4 h;
    #pragma unroll
    for (int jj = 0; jj < 4; ++jj) h[jj] = (_Float16)acc[jj];
    *(f16x4*)(aggE16 + (size_t)row * F_HID + lo) = h;
}

// ---------------------------------------------------------------------------
// Kernel 5: dec[8192,512] f32 = elu( aggE16[8192,256] @ W2 ). BM=128, BN=64,
// B panel resident in LDS; ELU fused; NT f32 stores.
// ---------------------------------------------------------------------------
__global__ __launch_bounds__(256)
void gemm2e(const _Float16* __restrict__ A, const _Float16* __restrict__ BT,
            float* __restrict__ C) {
    const int LDT = 72, LDB = 264;
    __shared__ _Float16 As[128 * LDT];
    __shared__ _Float16 Bs[64 * LDB];
    const int tid = threadIdx.x;
    const int wid = tid >> 6, lane = tid & 63;
    const int brow = (blockIdx.x >> 3) * 128;
    const int bcol = (blockIdx.x & 7) * 64;
    const int wr = (wid >> 1) * 64, wc = (wid & 1) * 32;

    #pragma unroll
    for (int i = 0; i < 8; ++i) {
        int id = tid + i * 256;
        int r = id >> 5, kc = (id & 31) * 8;
        *(f16x8*)&Bs[r * LDB + kc] = *(const f16x8*)&BT[(size_t)(bcol + r) * F_HID + kc];
    }

    f32x4 acc[4][2];
    #pragma unroll
    for (int m = 0; m < 4; ++m)
        #pragma unroll
        for (int n = 0; n < 2; ++n) acc[m][n] = f32x4{0.f, 0.f, 0.f, 0.f};

    for (int k0 = 0; k0 < F_HID; k0 += 64) {
        #pragma unroll
        for (int i = 0; i < 4; ++i) {
            int id = tid + i * 256;
            int r = id >> 3, kc = (id & 7) * 8;
            *(f16x8*)&As[r * LDT + kc] = *(const f16x8*)&A[(size_t)(brow + r) * F_HID + k0 + kc];
        }
        __syncthreads();
        #pragma unroll
        for (int ks = 0; ks < 2; ++ks) {
            const int kb = ks * 32 + (lane >> 4) * 8;
            f16x8 af[4], bfr[2];
            #pragma unroll
            for (int m = 0; m < 4; ++m)
                af[m] = *(const f16x8*)&As[(wr + m * 16 + (lane & 15)) * LDT + kb];
            #pragma unroll
            for (int n = 0; n < 2; ++n)
                bfr[n] = *(const f16x8*)&Bs[(wc + n * 16 + (lane & 15)) * LDB + k0 + kb];
            #pragma unroll
            for (int m = 0; m < 4; ++m)
                #pragma unroll
                for (int n = 0; n < 2; ++n)
                    acc[m][n] = __builtin_amdgcn_mfma_f32_16x16x32_f16(
                        af[m], bfr[n], acc[m][n], 0, 0, 0);
        }
        __syncthreads();
    }
    #pragma unroll
    for (int m = 0; m < 4; ++m)
        #pragma unroll
        for (int n = 0; n < 2; ++n) {
            int row = brow + wr + m * 16 + ((lane >> 4) << 2);
            int col = bcol + wc + n * 16 + (lane & 15);
            #pragma unroll
            for (int j = 0; j < 4; ++j) {
                float v = acc[m][n][j];
                float e = v > 0.0f ? v : (__expf(v) - 1.0f);
                __builtin_nontemporal_store(e, &C[(size_t)(row + j) * F_IN + col]);
            }
        }
}

// ---------------------------------------------------------------------------
extern "C" void kernel_launch(void* const* d_in, const int* in_sizes, int n_in,
                              void* d_out, int out_size, void* d_ws, size_t ws_size,
                              hipStream_t stream) {
    (void)in_sizes; (void)n_in; (void)out_size; (void)ws_size;
    const float* x   = (const float*)d_in[0];
    const float* adj = (const float*)d_in[1];
    const float* W1  = (const float*)d_in[2];
    const float* a1  = (const float*)d_in[3];
    const float* W2  = (const float*)d_in[4];
    const float* a2  = (const float*)d_in[5];

    float* dec = (float*)d_out;                           // [8192, 512] f32
    float* enc = dec + (size_t)N_NODES * F_IN;            // [8192, 256] f32

    int*      cols   = (int*)d_ws;                        // 8192*64
    int*      cnt    = cols + (size_t)N_NODES * MAXDEG;   // 8192
    float*    s1     = (float*)(cnt + N_NODES);           // 8192
    float*    t1     = s1 + N_NODES;                      // 8192
    float*    s2     = t1 + N_NODES;                      // 8192
    float*    t2     = s2 + N_NODES;                      // 8192
    float*    w2s    = t2 + N_NODES;                      // 256
    float*    w2t    = w2s + F_HID;                       // 256
    _Float16* Wh1    = (_Float16*)(w2t + F_HID);          // 8192*256 fp16
    _Float16* enc16  = Wh1 + (size_t)N_NODES * F_HID;     // 8192*256 fp16
    _Float16* aggE16 = enc16 + (size_t)N_NODES * F_HID;   // 8192*256 fp16
    _Float16* W1T    = aggE16 + (size_t)N_NODES * F_HID;  // 256*512 fp16
    _Float16* W2T    = W1T + (size_t)F_HID * F_IN;        // 512*256 fp16

    // 1. prep: transposes, w2s/w2t, zero s1/t1
    prep_kernel<<<260, 256, 0, stream>>>(W1, W2, W1T, W2T, a2, w2s, w2t, s1);

    // 2. csr scan (all rows) overlapped with layer-1 GEMM (BN=128, low bids)
    csr_and_gemm1<<<2304, 256, 0, stream>>>(adj, cols, cnt, x, W1T, Wh1, a1, s1, t1);

    // 3. layer-1 attention -> enc, enc16; epilogue s2/t2
    aggregate_l1<<<N_NODES / 4, 256, 0, stream>>>(Wh1, cols, cnt, s1, t1,
                                                  w2s, w2t, enc, enc16, s2, t2);

    // 4. layer-2 aggregate in input space: aggE = att2 @ enc
    aggregate_l2pre<<<N_NODES / 4, 256, 0, stream>>>(enc16, cols, cnt, s2, t2, aggE16);

    // 5. dec = elu(aggE @ W2)
    gemm2e<<<512, 256, 0, stream>>>(aggE16, W2T, dec);
}